// Round 11
// baseline (244.486 us; speedup 1.0000x reference)
//
#include <hip/hip_runtime.h>
#include <hip/hip_fp16.h>
#include <stdint.h>

typedef _Float16 f16;
typedef f16   f16x8 __attribute__((ext_vector_type(8)));
typedef float f32x4 __attribute__((ext_vector_type(4)));

#define NTOK 262144
#define DDIM 256
#define KCB  1024
#define GG   4
#define CC   64
#define WAVES 8                         // waves per block
#define FR   4                          // 16-row fragments per wave (64 rows/wave)
#define ROWS_PER_BLK (WAVES * FR * 16)  // 512
#define NBLKX (NTOK / ROWS_PER_BLK)     // 512
#define NPART (NBLKX * GG)              // 2048 per-block loss partials
#define KHALF 512                       // codes per LDS phase
#define CBH   (KHALF * CC * 2)          // 64 KB: half codebook fp16

static __device__ __forceinline__ uint32_t umin32(uint32_t a, uint32_t b) { return a < b ? a : b; }

typedef __attribute__((address_space(1))) const void gv_t;
typedef __attribute__((address_space(3))) void lv_t;
static __device__ __forceinline__ void gl_lds16(const void* g, void* l) {
    __builtin_amdgcn_global_load_lds((gv_t*)g, (lv_t*)l, 16, 0, 0);
}
static __device__ __forceinline__ void gl_lds4(const void* g, void* l) {
    __builtin_amdgcn_global_load_lds((gv_t*)g, (lv_t*)l, 4, 0, 0);
}

// ---------------- prep: fp32 codebook -> fp16 copy + (0.5 + ||e||^2) table
__global__ __launch_bounds__(64) void vq_prep(const float* __restrict__ cb,
                                              f16* __restrict__ cb16,
                                              float* __restrict__ esq05) {
    int gk = blockIdx.x;          // 0 .. G*K-1
    int c  = threadIdx.x;         // 0 .. 63
    float v = cb[(size_t)gk * CC + c];
    cb16[(size_t)gk * CC + c] = (f16)v;
    float s = v * v;
    #pragma unroll
    for (int off = 32; off; off >>= 1) s += __shfl_down(s, off, 64);
    if (c == 0) esq05[gk] = 0.5f + s;
}

// ---------------- kernel 1: fp16 16x16x32 MFMA argmin, half-codebook LDS phases,
// barrier-free sweep inside each phase (3 barriers total per block).
__global__ __launch_bounds__(512, 4) void vq_argmin(const float* __restrict__ z,
                                                    const f16* __restrict__ cb16,
                                                    const float* __restrict__ esq05,
                                                    unsigned short* __restrict__ idx,
                                                    float* __restrict__ part) {
    const int tid  = threadIdx.x;
    const int lane = tid & 63;
    const int w    = tid >> 6;                   // wave id (0..7)
    const int g    = blockIdx.y;                 // group
    const int r0   = blockIdx.x * ROWS_PER_BLK + w * (FR * 16);  // wave's base row
    const int q    = lane >> 4;                  // quarter (k-chunk selector)
    const int t    = lane & 15;                  // within-16 id

    // half codebook in read-slot-linear layout + e half-table
    __shared__ __align__(16) char sb[CBH + KHALF * 4];
    __shared__ float ls[WAVES];

    const f16*   cbg = cb16  + (size_t)g * KCB * CC;
    const float* eg  = esq05 + (size_t)g * KCB;

    // stage phase ph (512 codes, 64KB) into sb, read-slot-linear (0-conflict):
    // chunk c (1KB): subtile s=c>>1 (16 codes), half hf=c&1 (k 0..31 / 32..63);
    // lane (q,t) supplies code (s*16+t), k bytes q*8..q*8+7 of that half.
    #define STAGE(ph)                                                                 \
        do {                                                                          \
            _Pragma("unroll")                                                         \
            for (int j = 0; j < 8; ++j) {                                             \
                int c  = w + 8 * j;                                                   \
                int s  = c >> 1, hf = c & 1;                                          \
                const f16* src = cbg + ((size_t)((ph) * KHALF + s * 16 + t) * CC      \
                                        + hf * 32 + q * 8);                           \
                gl_lds16(src, &sb[c * 1024]);                                         \
            }                                                                         \
            gl_lds4(eg + (ph) * KHALF + tid, &sb[CBH + w * 256]);                     \
        } while (0)

    STAGE(0);

    // ---- load A fragments (FR x 16 rows, K=64 in two 32-halves), fp32 -> fp16, scaled by -2
    // A layout for mfma_f32_16x16x32_f16: lane holds row (lane&15), k = (lane>>4)*8 + j
    f16x8 a[FR][2];
    float zsq[FR];
    #pragma unroll
    for (int f = 0; f < FR; ++f) {
        int row = r0 + f * 16 + t;
        const float* zp = z + (size_t)row * DDIM + g * CC + q * 8;
        float4 v0 = *(const float4*)(zp);
        float4 v1 = *(const float4*)(zp + 4);
        float4 v2 = *(const float4*)(zp + 32);
        float4 v3 = *(const float4*)(zp + 36);
        f16x8 a0 = { (f16)(-2.f*v0.x),(f16)(-2.f*v0.y),(f16)(-2.f*v0.z),(f16)(-2.f*v0.w),
                     (f16)(-2.f*v1.x),(f16)(-2.f*v1.y),(f16)(-2.f*v1.z),(f16)(-2.f*v1.w) };
        f16x8 a1 = { (f16)(-2.f*v2.x),(f16)(-2.f*v2.y),(f16)(-2.f*v2.z),(f16)(-2.f*v2.w),
                     (f16)(-2.f*v3.x),(f16)(-2.f*v3.y),(f16)(-2.f*v3.z),(f16)(-2.f*v3.w) };
        a[f][0] = a0; a[f][1] = a1;
        float s = v0.x*v0.x + v0.y*v0.y + v0.z*v0.z + v0.w*v0.w
                + v1.x*v1.x + v1.y*v1.y + v1.z*v1.z + v1.w*v1.w
                + v2.x*v2.x + v2.y*v2.y + v2.z*v2.z + v2.w*v2.w
                + v3.x*v3.x + v3.y*v3.y + v3.z*v3.z + v3.w*v3.w;
        s += __shfl_xor(s, 16, 64);
        s += __shfl_xor(s, 32, 64);
        zsq[f] = s;   // lane l holds full ||z_g||^2 for row (l&15)
    }

    uint32_t run[FR][4];
    #pragma unroll
    for (int f = 0; f < FR; ++f)
        #pragma unroll
        for (int i = 0; i < 4; ++i) run[f][i] = 0xFFFFFFFFu;

    const float* eb = (const float*)(sb + CBH);

    // ---- two phases; barrier-free paired sweep inside each
    #pragma unroll 1
    for (int ph = 0; ph < 2; ++ph) {
        __syncthreads();                         // stage(ph) landed (drains vmcnt)
        // prefetch first subtile-pair of this phase
        f16x8 c0 = *(const f16x8*)(sb + lane * 16);
        f16x8 c1 = *(const f16x8*)(sb + 1024 + lane * 16);
        f16x8 c2 = *(const f16x8*)(sb + 2048 + lane * 16);
        f16x8 c3 = *(const f16x8*)(sb + 3072 + lane * 16);
        #pragma unroll 1
        for (int s2 = 0; s2 < 32; s2 += 2) {
            int ns = (s2 + 2) & 31;              // wrap -> harmless redundant load
            const char* pn = sb + (size_t)ns * 2048;
            f16x8 n0 = *(const f16x8*)(pn + lane * 16);
            f16x8 n1 = *(const f16x8*)(pn + 1024 + lane * 16);
            f16x8 n2 = *(const f16x8*)(pn + 2048 + lane * 16);
            f16x8 n3 = *(const f16x8*)(pn + 3072 + lane * 16);

            float eA = eb[s2 * 16 + t];
            float eB = eb[s2 * 16 + 16 + t];
            f32x4 ceA = { eA, eA, eA, eA };      // d = (0.5+esq) + (-2z)·e
            f32x4 ceB = { eB, eB, eB, eB };
            uint32_t codeA = (uint32_t)(ph * KHALF + s2 * 16 + t);
            #pragma unroll
            for (int f = 0; f < FR; ++f) {
                f32x4 accA = __builtin_amdgcn_mfma_f32_16x16x32_f16(a[f][0], c0, ceA, 0, 0, 0);
                accA = __builtin_amdgcn_mfma_f32_16x16x32_f16(a[f][1], c1, accA, 0, 0, 0);
                f32x4 accB = __builtin_amdgcn_mfma_f32_16x16x32_f16(a[f][0], c2, ceB, 0, 0, 0);
                accB = __builtin_amdgcn_mfma_f32_16x16x32_f16(a[f][1], c3, accB, 0, 0, 0);
                // C/D layout: col = lane&15 (code), row = (lane>>4)*4 + i
                #pragma unroll
                for (int i = 0; i < 4; ++i) {
                    uint32_t kA = (__float_as_uint(accA[i]) & 0xFFFFFC00u) | codeA;        // v_and_or_b32
                    uint32_t kB = (__float_as_uint(accB[i]) & 0xFFFFFC00u) | (codeA + 16); // v_and_or_b32
                    run[f][i] = umin32(run[f][i], umin32(kA, kB));                         // v_min3_u32
                }
            }
            c0 = n0; c1 = n1; c2 = n2; c3 = n3;
        }
        if (ph == 0) {
            __syncthreads();                     // all waves done reading half 0
            STAGE(1);
        }
    }

    // ---- epilogue: cross-lane argmin, u16 index store, loss partials
    // R4-verified pattern: __shfl UNCONDITIONAL; only scalar accumulate + store
    // under the divergent (t==0) branch (R5 lesson).
    float lsum = 0.0f;
    #pragma unroll
    for (int f = 0; f < FR; ++f) {
        #pragma unroll
        for (int i = 0; i < 4; ++i) {
            uint32_t k = run[f][i];
            k = umin32(k, __shfl_xor(k, 1, 64));
            k = umin32(k, __shfl_xor(k, 2, 64));
            k = umin32(k, __shfl_xor(k, 4, 64));
            k = umin32(k, __shfl_xor(k, 8, 64));   // 16 lanes of each quarter agree
            int   kw     = (int)(k & 1023u);
            float minval = __uint_as_float(k & 0xFFFFFC00u) - 0.5f;  // esq - 2*dot (truncated)
            int rloc = q * 4 + i;                  // row within this 16-row fragment
            int grow = r0 + f * 16 + rloc;         // global row
            float zs = __shfl(zsq[f], rloc, 64);   // ||z_g||^2 of row rloc
            if (t == 0) {
                idx[(grow << 2) | g] = (unsigned short)kw;
                lsum += zs + minval;               // sum_c (zq - zg)^2 for this (row, group)
            }
        }
    }
    #pragma unroll
    for (int off = 32; off; off >>= 1) lsum += __shfl_down(lsum, off, 64);

    if (lane == 0) ls[w] = lsum;
    __syncthreads();
    if (tid == 0) {
        float s = 0.0f;
        #pragma unroll
        for (int i = 0; i < WAVES; ++i) s += ls[i];
        part[blockIdx.y * NBLKX + blockIdx.x] = s;
    }
}

// ---------------- kernel 2: gather exact fp32 codebook rows -> streaming output
__global__ __launch_bounds__(256) void vq_gather(const unsigned short* __restrict__ idx,
                                                 const float* __restrict__ cb32,
                                                 float* __restrict__ out) {
    const int stride = gridDim.x * 256;
    const int total  = NTOK * (DDIM / 4);              // 16.7M float4s
    for (int i = blockIdx.x * 256 + threadIdx.x; i < total; i += stride) {
        int row = i >> 6;                              // output row
        int d4  = i & 63;                              // float4 index within row
        int g   = d4 >> 4;
        int c4  = d4 & 15;
        int k   = idx[(row << 2) | g];
        float4 v = *(const float4*)(cb32 + (size_t)(((g << 10) + k) << 6) + (c4 << 2));
        *(float4*)(out + ((size_t)row << 8) + (d4 << 2)) = v;
    }
}

// ---------------- finalize: reduce per-block partials into the loss scalar
__global__ __launch_bounds__(256) void vq_final(const float* __restrict__ part,
                                                float* __restrict__ out_loss) {
    __shared__ float ls[4];
    float s = 0.0f;
    for (int i = threadIdx.x; i < NPART; i += 256) s += part[i];
    #pragma unroll
    for (int off = 32; off; off >>= 1) s += __shfl_down(s, off, 64);
    int lane = threadIdx.x & 63, w = threadIdx.x >> 6;
    if (lane == 0) ls[w] = s;
    __syncthreads();
    if (threadIdx.x == 0) {
        // loss = mean_g(BETA*commit + embed) = 1.5 * total_sq_err / (N*D)
        *out_loss = 1.5f * (ls[0] + ls[1] + ls[2] + ls[3]) * (1.0f / ((float)NTOK * (float)DDIM));
    }
}

extern "C" void kernel_launch(void* const* d_in, const int* in_sizes, int n_in,
                              void* d_out, int out_size, void* d_ws, size_t ws_size,
                              hipStream_t stream) {
    const float* z  = (const float*)d_in[0];
    const float* cb = (const float*)d_in[1];
    float* out = (float*)d_out;

    char* ws = (char*)d_ws;
    f16*   cb16  = (f16*)ws;                                           // 512 KB
    float* esq05 = (float*)(ws + 512 * 1024);                          // 16 KB
    float* part  = (float*)(ws + 512 * 1024 + 16 * 1024);              // 16 KB
    unsigned short* idx = (unsigned short*)(ws + 512 * 1024 + 32 * 1024); // 2 MB

    vq_prep<<<GG * KCB, 64, 0, stream>>>(cb, cb16, esq05);

    dim3 grid(NBLKX, GG);   // 512 x 4 = 2048 blocks, 2 resident/CU (8 waves each)
    vq_argmin<<<grid, 512, 0, stream>>>(z, cb16, esq05, idx, part);

    vq_gather<<<4096, 256, 0, stream>>>(idx, cb, out);

    vq_final<<<1, 256, 0, stream>>>(part, out + (size_t)NTOK * DDIM);
}